// Round 8
// baseline (113.297 us; speedup 1.0000x reference)
//
#include <hip/hip_runtime.h>

// Fake-quant (UniformAffineQuantizer): per-128-element-group asymmetric 4-bit
// fake quantization of an 8192x8192 f32 tensor.
//
// Mapping: each lane loads one float4. A group of 128 elems = 32 consecutive
// lanes; group min/max via 5-step __shfl_xor butterfly (width 32).
//
// NUMERICS LOG (deducing the reference chain):
//  R1/R2/R4: exact IEEE-f32 RNE chain (proven via Markstein soft-div == '/')
//            -> 0.38671875.       R5: x*RN(1/s) variant -> identical 0.387.
//  R3: exact f64 RNE chain -> 0.40625.  R6 exact-AFZ / R7 floor(t+.5):
//            both -> 0.40625.
//  Tie-rule algebra: ref must round one pos-even-tie UP (e1) and another
//  DOWN (e2) -- impossible for any tie rule at true ties => ref's SCALE
//  differs from RN(r/15) by 1 ulp in some groups (displacing e1's tie) and
//  matches in others (e2 stays a tie, resolved RNE). Mechanism: XLA rewrites
//  divide-by-broadcast into multiply-by-reciprocal:
//    scale = RN(r * RN(1/15))          [divide by broadcast const 15]
//    q     = RNE(x * RN(1/scale))      [divide by broadcast [G,1] scale]
//  while -xmin/scale ([G,1]/[G,1], not a broadcast) stays a true divide.
//  This round mirrors that chain exactly, all f32, RNE rounds.

__global__ __launch_bounds__(256) void fakequant_g128(
    const float4* __restrict__ x, float4* __restrict__ out, int nvec)
{
    const float C15 = 1.0f / 15.0f;   // constant-folded RN(1/15) = 0x3D888889

    const int stride = gridDim.x * blockDim.x;
    for (int v = blockIdx.x * blockDim.x + threadIdx.x; v < nvec; v += stride) {
        float4 d = x[v];

        float mn = fminf(fminf(d.x, d.y), fminf(d.z, d.w));
        float mx = fmaxf(fmaxf(d.x, d.y), fmaxf(d.z, d.w));

        // reduce min/max across the 32 lanes that form one 128-elem group
        #pragma unroll
        for (int off = 16; off > 0; off >>= 1) {
            mn = fminf(mn, __shfl_xor(mn, off, 32));
            mx = fmaxf(mx, __shfl_xor(mx, off, 32));
        }

        // scale = clip((max-min) * RN(1/15), 1e-5, 1e4)  [XLA const-recip]
        float s = (mx - mn) * C15;
        s = fminf(fmaxf(s, 1e-5f), 1e4f);

        // zero_point = clip(-min / s, -1e4, 1e4)  [true divide], RNE round
        float zp = (-mn) / s;
        zp = fminf(fmaxf(zp, -1e4f), 1e4f);
        float rzp = rintf(zp);

        // q = RNE(x * RN(1/s))  [XLA broadcast-divide -> mul by reciprocal]
        float rs = 1.0f / s;     // true IEEE divide, once per group

        float4 o;
        o.x = (fminf(fmaxf(rintf(d.x * rs) + rzp, 0.0f), 15.0f) - rzp) * s;
        o.y = (fminf(fmaxf(rintf(d.y * rs) + rzp, 0.0f), 15.0f) - rzp) * s;
        o.z = (fminf(fmaxf(rintf(d.z * rs) + rzp, 0.0f), 15.0f) - rzp) * s;
        o.w = (fminf(fmaxf(rintf(d.w * rs) + rzp, 0.0f), 15.0f) - rzp) * s;

        out[v] = o;
    }
}

extern "C" void kernel_launch(void* const* d_in, const int* in_sizes, int n_in,
                              void* d_out, int out_size, void* d_ws, size_t ws_size,
                              hipStream_t stream)
{
    const float* x = (const float*)d_in[0];
    float* o = (float*)d_out;

    const int n = in_sizes[0];          // 8192*8192 = 67108864
    const int nvec = n / 4;             // 16777216 float4 elements

    const int block = 256;
    const int grid = 2048;              // grid-stride; stride preserves the
                                        // 32-lane <-> 128-elem group alignment

    fakequant_g128<<<grid, block, 0, stream>>>(
        (const float4*)x, (float4*)o, nvec);
}